// Round 1
// baseline (138.487 us; speedup 1.0000x reference)
//
#include <hip/hip_runtime.h>

namespace {

struct M3 { float a[9]; };
struct V3 { float x, y, z; };

// p' = R*o + p  (9 FMAs)
__device__ __forceinline__ V3 mulv_add(const M3& R, V3 o, V3 p) {
    V3 r;
    r.x = fmaf(R.a[0], o.x, fmaf(R.a[1], o.y, fmaf(R.a[2], o.z, p.x)));
    r.y = fmaf(R.a[3], o.x, fmaf(R.a[4], o.y, fmaf(R.a[5], o.z, p.y)));
    r.z = fmaf(R.a[6], o.x, fmaf(R.a[7], o.y, fmaf(R.a[8], o.z, p.z)));
    return r;
}

// D = R*A (row-major 3x3), 9 mul + 18 fma
__device__ __forceinline__ M3 mulm(const M3& R, const M3& A) {
    M3 D;
#pragma unroll
    for (int i = 0; i < 3; ++i) {
#pragma unroll
        for (int k = 0; k < 3; ++k) {
            D.a[i*3+k] = fmaf(R.a[i*3+0], A.a[0*3+k],
                         fmaf(R.a[i*3+1], A.a[1*3+k],
                              R.a[i*3+2] * A.a[2*3+k]));
        }
    }
    return D;
}

// extract float at compile-time relative index REL from a float4 span
template <int REL>
__device__ __forceinline__ float getf(const float4* s) {
    constexpr int Q = REL >> 2;
    constexpr int C = REL & 3;
    if constexpr (C == 0) return s[Q].x;
    else if constexpr (C == 1) return s[Q].y;
    else if constexpr (C == 2) return s[Q].z;
    else return s[Q].w;
}

// load 3x3 matrix of joint J from a span whose first float index is BASE
template <int J, int BASE>
__device__ __forceinline__ M3 loadA(const float4* s) {
    constexpr int K = 9 * J - BASE;
    M3 A;
    A.a[0] = getf<K+0>(s); A.a[1] = getf<K+1>(s); A.a[2] = getf<K+2>(s);
    A.a[3] = getf<K+3>(s); A.a[4] = getf<K+4>(s); A.a[5] = getf<K+5>(s);
    A.a[6] = getf<K+6>(s); A.a[7] = getf<K+7>(s); A.a[8] = getf<K+8>(s);
    return A;
}

__device__ __forceinline__ V3 loadOff(const float* __restrict__ off, int j) {
    V3 o; o.x = off[3*j+0]; o.y = off[3*j+1]; o.z = off[3*j+2]; return o;
}

#define STORE_P(J, P) do { ob[3*(J)+0] = (P).x; ob[3*(J)+1] = (P).y; ob[3*(J)+2] = (P).z; } while (0)

__global__ __launch_bounds__(256)
void fk_kernel(const float* __restrict__ ja, const float* __restrict__ off,
               float* __restrict__ out, int N) {
    int n = blockIdx.x * blockDim.x + threadIdx.x;
    if (n >= N) return;

    const float4* v4 = reinterpret_cast<const float4*>(ja) + (size_t)n * 54;

    float ob[72];
    ob[0] = 0.f; ob[1] = 0.f; ob[2] = 0.f;   // root position = 0

    // ---- span 1: floats [8, 92) = v4[2..22]  (covers A_1..A_9) ----
    float4 s1[21];
#pragma unroll
    for (int q = 0; q < 21; ++q) s1[q] = v4[2 + q];
    constexpr int B1 = 8;

    // root rotation forced to identity: p_{1,2,3} = off, R = A
    V3 p1 = loadOff(off, 1), p2 = loadOff(off, 2), p3 = loadOff(off, 3);
    STORE_P(1, p1); STORE_P(2, p2); STORE_P(3, p3);
    M3 R1 = loadA<1, B1>(s1);
    M3 R2 = loadA<2, B1>(s1);
    M3 R3 = loadA<3, B1>(s1);

    V3 p4 = mulv_add(R1, loadOff(off, 4), p1);  M3 R4 = mulm(R1, loadA<4, B1>(s1));  STORE_P(4, p4);
    V3 p5 = mulv_add(R2, loadOff(off, 5), p2);  M3 R5 = mulm(R2, loadA<5, B1>(s1));  STORE_P(5, p5);
    V3 p6 = mulv_add(R3, loadOff(off, 6), p3);  M3 R6 = mulm(R3, loadA<6, B1>(s1));  STORE_P(6, p6);
    V3 p7 = mulv_add(R4, loadOff(off, 7), p4);  M3 R7 = mulm(R4, loadA<7, B1>(s1));  STORE_P(7, p7);
    V3 p8 = mulv_add(R5, loadOff(off, 8), p5);  M3 R8 = mulm(R5, loadA<8, B1>(s1));  STORE_P(8, p8);
    V3 p9 = mulv_add(R6, loadOff(off, 9), p6);  M3 R9 = mulm(R6, loadA<9, B1>(s1));  STORE_P(9, p9);

    // leaves of the legs: positions only (A_10, A_11 never needed)
    V3 p10 = mulv_add(R7, loadOff(off, 10), p7);  STORE_P(10, p10);
    V3 p11 = mulv_add(R8, loadOff(off, 11), p8);  STORE_P(11, p11);

    // ---- span 2: floats [108, 136) = v4[27..33]  (covers A_12..A_14) ----
    float4 s2[7];
#pragma unroll
    for (int q = 0; q < 7; ++q) s2[q] = v4[27 + q];
    constexpr int B2 = 108;

    V3 p12 = mulv_add(R9, loadOff(off, 12), p9);  M3 R12 = mulm(R9, loadA<12, B2>(s2));  STORE_P(12, p12);
    V3 p13 = mulv_add(R9, loadOff(off, 13), p9);  M3 R13 = mulm(R9, loadA<13, B2>(s2));  STORE_P(13, p13);
    V3 p14 = mulv_add(R9, loadOff(off, 14), p9);  M3 R14 = mulm(R9, loadA<14, B2>(s2));  STORE_P(14, p14);
    V3 p15 = mulv_add(R12, loadOff(off, 15), p12);  STORE_P(15, p15);  // head leaf

    // ---- span 3: floats [144, 200) = v4[36..49]  (covers A_16..A_21) ----
    float4 s3[14];
#pragma unroll
    for (int q = 0; q < 14; ++q) s3[q] = v4[36 + q];
    constexpr int B3 = 144;

    V3 p16 = mulv_add(R13, loadOff(off, 16), p13);  M3 R16 = mulm(R13, loadA<16, B3>(s3));  STORE_P(16, p16);
    V3 p17 = mulv_add(R14, loadOff(off, 17), p14);  M3 R17 = mulm(R14, loadA<17, B3>(s3));  STORE_P(17, p17);
    V3 p18 = mulv_add(R16, loadOff(off, 18), p16);  M3 R18 = mulm(R16, loadA<18, B3>(s3));  STORE_P(18, p18);
    V3 p19 = mulv_add(R17, loadOff(off, 19), p17);  M3 R19 = mulm(R17, loadA<19, B3>(s3));  STORE_P(19, p19);
    V3 p20 = mulv_add(R18, loadOff(off, 20), p18);  M3 R20 = mulm(R18, loadA<20, B3>(s3));  STORE_P(20, p20);
    V3 p21 = mulv_add(R19, loadOff(off, 21), p19);  M3 R21 = mulm(R19, loadA<21, B3>(s3));  STORE_P(21, p21);

    V3 p22 = mulv_add(R20, loadOff(off, 22), p20);  STORE_P(22, p22);  // hand leaves
    V3 p23 = mulv_add(R21, loadOff(off, 23), p21);  STORE_P(23, p23);

    // ---- vectorized output: 18 aligned float4 stores ----
    float4* o4 = reinterpret_cast<float4*>(out) + (size_t)n * 18;
#pragma unroll
    for (int q = 0; q < 18; ++q) {
        float4 w;
        w.x = ob[4*q+0]; w.y = ob[4*q+1]; w.z = ob[4*q+2]; w.w = ob[4*q+3];
        o4[q] = w;
    }
}

}  // namespace

extern "C" void kernel_launch(void* const* d_in, const int* in_sizes, int n_in,
                              void* d_out, int out_size, void* d_ws, size_t ws_size,
                              hipStream_t stream) {
    const float* ja  = (const float*)d_in[0];
    const float* off = (const float*)d_in[1];
    float* out = (float*)d_out;

    int N = in_sizes[0] / 216;   // 24 joints * 9
    int block = 256;
    int grid = (N + block - 1) / block;
    hipLaunchKernelGGL(fk_kernel, dim3(grid), dim3(block), 0, stream, ja, off, out, N);
}

// Round 2
// 70.236 us; speedup vs baseline: 1.9717x; 1.9717x over previous
//
#include <hip/hip_runtime.h>

namespace {

struct M3 { float a[9]; };
struct V3 { float x, y, z; };

__device__ __forceinline__ V3 mulv_add(const M3& R, V3 o, V3 p) {
    V3 r;
    r.x = fmaf(R.a[0], o.x, fmaf(R.a[1], o.y, fmaf(R.a[2], o.z, p.x)));
    r.y = fmaf(R.a[3], o.x, fmaf(R.a[4], o.y, fmaf(R.a[5], o.z, p.y)));
    r.z = fmaf(R.a[6], o.x, fmaf(R.a[7], o.y, fmaf(R.a[8], o.z, p.z)));
    return r;
}

__device__ __forceinline__ M3 mulm(const M3& R, const M3& A) {
    M3 D;
#pragma unroll
    for (int i = 0; i < 3; ++i) {
#pragma unroll
        for (int k = 0; k < 3; ++k) {
            D.a[i*3+k] = fmaf(R.a[i*3+0], A.a[0*3+k],
                         fmaf(R.a[i*3+1], A.a[1*3+k],
                              R.a[i*3+2] * A.a[2*3+k]));
        }
    }
    return D;
}

template <int REL>
__device__ __forceinline__ float getf(const float4* s) {
    constexpr int Q = REL >> 2;
    constexpr int C = REL & 3;
    if constexpr (C == 0) return s[Q].x;
    else if constexpr (C == 1) return s[Q].y;
    else if constexpr (C == 2) return s[Q].z;
    else return s[Q].w;
}

template <int J, int BASE>
__device__ __forceinline__ M3 loadA(const float4* s) {
    constexpr int K = 9 * J - BASE;
    M3 A;
    A.a[0] = getf<K+0>(s); A.a[1] = getf<K+1>(s); A.a[2] = getf<K+2>(s);
    A.a[3] = getf<K+3>(s); A.a[4] = getf<K+4>(s); A.a[5] = getf<K+5>(s);
    A.a[6] = getf<K+6>(s); A.a[7] = getf<K+7>(s); A.a[8] = getf<K+8>(s);
    return A;
}

__device__ __forceinline__ V3 loadOff(const float* __restrict__ off, int j) {
    V3 o; o.x = off[3*j+0]; o.y = off[3*j+1]; o.z = off[3*j+2]; return o;
}

// LDS output staging: [thread][76] floats (stride 76 words: 16B-aligned rows,
// gcd(76,32)=4 -> only 4-way bank aliasing on scalar writes, ~free)
#define LPOS(J, P) do { lout[t][3*(J)+0] = (P).x; lout[t][3*(J)+1] = (P).y; lout[t][3*(J)+2] = (P).z; } while (0)

__global__ __launch_bounds__(128, 2)
void fk_kernel(const float* __restrict__ ja, const float* __restrict__ off,
               float* __restrict__ out, int N) {
    __shared__ __align__(16) float lout[128][76];

    const int t = threadIdx.x;            // 0..127
    const int w = t >> 6, l = t & 63;
    const int n = blockIdx.x * 128 + t;   // sample index (N divisible by 128)

    const float4* v4 = reinterpret_cast<const float4*>(ja) + (size_t)n * 54;

    // ---- all input loads issued up front: 42 float4 in flight per lane ----
    float4 s1[21];   // floats [8,92)    = A_1..A_9
#pragma unroll
    for (int q = 0; q < 21; ++q) s1[q] = v4[2 + q];
    float4 s2[7];    // floats [108,136) = A_12..A_14
#pragma unroll
    for (int q = 0; q < 7; ++q) s2[q] = v4[27 + q];
    float4 s3[14];   // floats [144,200) = A_16..A_21
#pragma unroll
    for (int q = 0; q < 14; ++q) s3[q] = v4[36 + q];

    constexpr int B1 = 8, B2 = 108, B3 = 144;

    lout[t][0] = 0.f; lout[t][1] = 0.f; lout[t][2] = 0.f;  // root

    // root rotation = identity: R_j = A_j, p_j = off_j for j in {1,2,3}
    V3 p1 = loadOff(off, 1), p2 = loadOff(off, 2), p3 = loadOff(off, 3);
    LPOS(1, p1); LPOS(2, p2); LPOS(3, p3);
    M3 R1 = loadA<1, B1>(s1);
    M3 R2 = loadA<2, B1>(s1);
    M3 R3 = loadA<3, B1>(s1);

    V3 p4 = mulv_add(R1, loadOff(off, 4), p1);  M3 R4 = mulm(R1, loadA<4, B1>(s1));  LPOS(4, p4);
    V3 p5 = mulv_add(R2, loadOff(off, 5), p2);  M3 R5 = mulm(R2, loadA<5, B1>(s1));  LPOS(5, p5);
    V3 p6 = mulv_add(R3, loadOff(off, 6), p3);  M3 R6 = mulm(R3, loadA<6, B1>(s1));  LPOS(6, p6);
    V3 p7 = mulv_add(R4, loadOff(off, 7), p4);  M3 R7 = mulm(R4, loadA<7, B1>(s1));  LPOS(7, p7);
    V3 p8 = mulv_add(R5, loadOff(off, 8), p5);  M3 R8 = mulm(R5, loadA<8, B1>(s1));  LPOS(8, p8);
    V3 p9 = mulv_add(R6, loadOff(off, 9), p6);  M3 R9 = mulm(R6, loadA<9, B1>(s1));  LPOS(9, p9);

    V3 p10 = mulv_add(R7, loadOff(off, 10), p7);  LPOS(10, p10);   // leaf
    V3 p11 = mulv_add(R8, loadOff(off, 11), p8);  LPOS(11, p11);   // leaf

    V3 p12 = mulv_add(R9, loadOff(off, 12), p9);  M3 R12 = mulm(R9, loadA<12, B2>(s2));  LPOS(12, p12);
    V3 p13 = mulv_add(R9, loadOff(off, 13), p9);  M3 R13 = mulm(R9, loadA<13, B2>(s2));  LPOS(13, p13);
    V3 p14 = mulv_add(R9, loadOff(off, 14), p9);  M3 R14 = mulm(R9, loadA<14, B2>(s2));  LPOS(14, p14);
    V3 p15 = mulv_add(R12, loadOff(off, 15), p12);  LPOS(15, p15); // head leaf

    V3 p16 = mulv_add(R13, loadOff(off, 16), p13);  M3 R16 = mulm(R13, loadA<16, B3>(s3));  LPOS(16, p16);
    V3 p17 = mulv_add(R14, loadOff(off, 17), p14);  M3 R17 = mulm(R14, loadA<17, B3>(s3));  LPOS(17, p17);
    V3 p18 = mulv_add(R16, loadOff(off, 18), p16);  M3 R18 = mulm(R16, loadA<18, B3>(s3));  LPOS(18, p18);
    V3 p19 = mulv_add(R17, loadOff(off, 19), p17);  M3 R19 = mulm(R17, loadA<19, B3>(s3));  LPOS(19, p19);
    V3 p20 = mulv_add(R18, loadOff(off, 20), p18);  M3 R20 = mulm(R18, loadA<20, B3>(s3));  LPOS(20, p20);
    V3 p21 = mulv_add(R19, loadOff(off, 21), p19);  M3 R21 = mulm(R19, loadA<21, B3>(s3));  LPOS(21, p21);

    V3 p22 = mulv_add(R20, loadOff(off, 22), p20);  LPOS(22, p22); // hand leaf
    V3 p23 = mulv_add(R21, loadOff(off, 23), p21);  LPOS(23, p23); // hand leaf

    // ---- coalesced output: wave streams its 64 samples' positions ----
    // Within-wave LDS write->read dependency: lockstep wave, compiler inserts
    // lgkmcnt waits; no barrier needed (each wave touches only its own rows).
    float4* o4 = reinterpret_cast<float4*>(out);
    const size_t base4 = ((size_t)blockIdx.x * 128 + w * 64) * 18;
#pragma unroll
    for (int i = 0; i < 18; ++i) {
        int e4 = i * 64 + l;            // float4 index within wave's region
        int s  = e4 / 18;               // local sample (const-div -> magic mul)
        int r  = e4 - s * 18;           // float4 within sample
        const float4* lp = reinterpret_cast<const float4*>(&lout[w * 64 + s][4 * r]);
        o4[base4 + e4] = *lp;
    }
}

}  // namespace

extern "C" void kernel_launch(void* const* d_in, const int* in_sizes, int n_in,
                              void* d_out, int out_size, void* d_ws, size_t ws_size,
                              hipStream_t stream) {
    const float* ja  = (const float*)d_in[0];
    const float* off = (const float*)d_in[1];
    float* out = (float*)d_out;

    int N = in_sizes[0] / 216;   // 24 joints * 9
    int block = 128;
    int grid = (N + block - 1) / block;
    hipLaunchKernelGGL(fk_kernel, dim3(grid), dim3(block), 0, stream, ja, off, out, N);
}

// Round 4
// 53.815 us; speedup vs baseline: 2.5734x; 1.3051x over previous
//
#include <hip/hip_runtime.h>

namespace {

typedef float v4f __attribute__((ext_vector_type(4)));

struct M3 { float a[9]; };
struct V3 { float x, y, z; };

__device__ __forceinline__ V3 mulv_add(const M3& R, V3 o, V3 p) {
    V3 r;
    r.x = fmaf(R.a[0], o.x, fmaf(R.a[1], o.y, fmaf(R.a[2], o.z, p.x)));
    r.y = fmaf(R.a[3], o.x, fmaf(R.a[4], o.y, fmaf(R.a[5], o.z, p.y)));
    r.z = fmaf(R.a[6], o.x, fmaf(R.a[7], o.y, fmaf(R.a[8], o.z, p.z)));
    return r;
}

__device__ __forceinline__ M3 mulm(const M3& R, const M3& A) {
    M3 D;
#pragma unroll
    for (int i = 0; i < 3; ++i) {
#pragma unroll
        for (int k = 0; k < 3; ++k) {
            D.a[i*3+k] = fmaf(R.a[i*3+0], A.a[0*3+k],
                         fmaf(R.a[i*3+1], A.a[1*3+k],
                              R.a[i*3+2] * A.a[2*3+k]));
        }
    }
    return D;
}

template <int REL>
__device__ __forceinline__ float getf(const float4* s) {
    constexpr int Q = REL >> 2;
    constexpr int C = REL & 3;
    if constexpr (C == 0) return s[Q].x;
    else if constexpr (C == 1) return s[Q].y;
    else if constexpr (C == 2) return s[Q].z;
    else return s[Q].w;
}

template <int J, int BASE>
__device__ __forceinline__ M3 loadA(const float4* s) {
    constexpr int K = 9 * J - BASE;
    M3 A;
    A.a[0] = getf<K+0>(s); A.a[1] = getf<K+1>(s); A.a[2] = getf<K+2>(s);
    A.a[3] = getf<K+3>(s); A.a[4] = getf<K+4>(s); A.a[5] = getf<K+5>(s);
    A.a[6] = getf<K+6>(s); A.a[7] = getf<K+7>(s); A.a[8] = getf<K+8>(s);
    return A;
}

__device__ __forceinline__ V3 loadOff(const float* __restrict__ off, int j) {
    V3 o; o.x = off[3*j+0]; o.y = off[3*j+1]; o.z = off[3*j+2]; return o;
}

// positions accumulate in a statically-indexed register array (rule #20 safe)
#define OBP(J, P) do { ob[3*(J)+0] = (P).x; ob[3*(J)+1] = (P).y; ob[3*(J)+2] = (P).z; } while (0)

__global__ __launch_bounds__(128, 2)
void fk_kernel(const float* __restrict__ ja, const float* __restrict__ off,
               float* __restrict__ out, int N) {
    // Transposed + padded staging: stage[wave][r][sample]. Row pad 65 (not 64)
    // makes both the write (lane t -> [r][t]) and the strided read bank-free:
    // word addr = ((w*18+r)*65 + s)*4 -> bank = (4r+4s)%32, each 16-lane
    // quarter hits every bank exactly twice (minimum for wave64 = free).
    __shared__ __align__(16) float4 stage[2][18][65];

    const int t = threadIdx.x;            // 0..127
    const int w = t >> 6, l = t & 63;
    const int n = blockIdx.x * 128 + t;   // N divisible by 128

    const float4* v4 = reinterpret_cast<const float4*>(ja) + (size_t)n * 54;

    // ---- all input loads issued up front (42 float4 in flight / lane) ----
    float4 s1[21];   // floats [8,92)    = A_1..A_9
#pragma unroll
    for (int q = 0; q < 21; ++q) s1[q] = v4[2 + q];
    float4 s2[7];    // floats [108,136) = A_12..A_14
#pragma unroll
    for (int q = 0; q < 7; ++q) s2[q] = v4[27 + q];
    float4 s3[14];   // floats [144,200) = A_16..A_21
#pragma unroll
    for (int q = 0; q < 14; ++q) s3[q] = v4[36 + q];

    constexpr int B1 = 8, B2 = 108, B3 = 144;

    float ob[72];
    ob[0] = 0.f; ob[1] = 0.f; ob[2] = 0.f;   // root position

    V3 p1 = loadOff(off, 1), p2 = loadOff(off, 2), p3 = loadOff(off, 3);
    OBP(1, p1); OBP(2, p2); OBP(3, p3);
    M3 R1 = loadA<1, B1>(s1);
    M3 R2 = loadA<2, B1>(s1);
    M3 R3 = loadA<3, B1>(s1);

    V3 p4 = mulv_add(R1, loadOff(off, 4), p1);  M3 R4 = mulm(R1, loadA<4, B1>(s1));  OBP(4, p4);
    V3 p5 = mulv_add(R2, loadOff(off, 5), p2);  M3 R5 = mulm(R2, loadA<5, B1>(s1));  OBP(5, p5);
    V3 p6 = mulv_add(R3, loadOff(off, 6), p3);  M3 R6 = mulm(R3, loadA<6, B1>(s1));  OBP(6, p6);
    V3 p7 = mulv_add(R4, loadOff(off, 7), p4);  M3 R7 = mulm(R4, loadA<7, B1>(s1));  OBP(7, p7);
    V3 p8 = mulv_add(R5, loadOff(off, 8), p5);  M3 R8 = mulm(R5, loadA<8, B1>(s1));  OBP(8, p8);
    V3 p9 = mulv_add(R6, loadOff(off, 9), p6);  M3 R9 = mulm(R6, loadA<9, B1>(s1));  OBP(9, p9);

    V3 p10 = mulv_add(R7, loadOff(off, 10), p7);  OBP(10, p10);   // leaf
    V3 p11 = mulv_add(R8, loadOff(off, 11), p8);  OBP(11, p11);   // leaf

    V3 p12 = mulv_add(R9, loadOff(off, 12), p9);  M3 R12 = mulm(R9, loadA<12, B2>(s2));  OBP(12, p12);
    V3 p13 = mulv_add(R9, loadOff(off, 13), p9);  M3 R13 = mulm(R9, loadA<13, B2>(s2));  OBP(13, p13);
    V3 p14 = mulv_add(R9, loadOff(off, 14), p9);  M3 R14 = mulm(R9, loadA<14, B2>(s2));  OBP(14, p14);
    V3 p15 = mulv_add(R12, loadOff(off, 15), p12);  OBP(15, p15); // head leaf

    V3 p16 = mulv_add(R13, loadOff(off, 16), p13);  M3 R16 = mulm(R13, loadA<16, B3>(s3));  OBP(16, p16);
    V3 p17 = mulv_add(R14, loadOff(off, 17), p14);  M3 R17 = mulm(R14, loadA<17, B3>(s3));  OBP(17, p17);
    V3 p18 = mulv_add(R16, loadOff(off, 18), p16);  M3 R18 = mulm(R16, loadA<18, B3>(s3));  OBP(18, p18);
    V3 p19 = mulv_add(R17, loadOff(off, 19), p17);  M3 R19 = mulm(R17, loadA<19, B3>(s3));  OBP(19, p19);
    V3 p20 = mulv_add(R18, loadOff(off, 20), p18);  M3 R20 = mulm(R18, loadA<20, B3>(s3));  OBP(20, p20);
    V3 p21 = mulv_add(R19, loadOff(off, 21), p19);  M3 R21 = mulm(R19, loadA<21, B3>(s3));  OBP(21, p21);

    V3 p22 = mulv_add(R20, loadOff(off, 22), p20);  OBP(22, p22); // hand leaf
    V3 p23 = mulv_add(R21, loadOff(off, 23), p21);  OBP(23, p23); // hand leaf

    // ---- pack 72 floats -> 18 float4, conflict-free LDS write ----
#pragma unroll
    for (int r = 0; r < 18; ++r) {
        float4 v;
        v.x = ob[4*r+0]; v.y = ob[4*r+1]; v.z = ob[4*r+2]; v.w = ob[4*r+3];
        stage[w][r][l] = v;
    }

    // ---- coalesced, nontemporal output (bypass caches: keep input resident)
    // Within-wave LDS write->read only (each wave owns stage[w]); lockstep
    // wave64 + compiler lgkmcnt waits, no barrier needed.
    v4f* o4 = reinterpret_cast<v4f*>(out);
    const size_t base4 = ((size_t)blockIdx.x * 128 + w * 64) * 18;
#pragma unroll
    for (int i = 0; i < 18; ++i) {
        int e4 = i * 64 + l;            // float4 index in wave's 1152-f4 region
        int s  = e4 / 18;               // local sample (magic-mul)
        int r  = e4 - s * 18;
        float4 v = stage[w][r][s];
        v4f vv; vv.x = v.x; vv.y = v.y; vv.z = v.z; vv.w = v.w;
        __builtin_nontemporal_store(vv, &o4[base4 + e4]);
    }
}

}  // namespace

extern "C" void kernel_launch(void* const* d_in, const int* in_sizes, int n_in,
                              void* d_out, int out_size, void* d_ws, size_t ws_size,
                              hipStream_t stream) {
    const float* ja  = (const float*)d_in[0];
    const float* off = (const float*)d_in[1];
    float* out = (float*)d_out;

    int N = in_sizes[0] / 216;   // 24 joints * 9
    int block = 128;
    int grid = (N + block - 1) / block;
    hipLaunchKernelGGL(fk_kernel, dim3(grid), dim3(block), 0, stream, ja, off, out, N);
}